// Round 1
// baseline (417.123 us; speedup 1.0000x reference)
//
#include <hip/hip_runtime.h>
#include <cstdint>

typedef float floatx4 __attribute__((ext_vector_type(4)));
typedef __bf16 bf16x8 __attribute__((ext_vector_type(8)));

__device__ __forceinline__ unsigned short f2b(float f) {
  union { float f; unsigned u; } v; v.f = f;
  return (unsigned short)((v.u + 0x7FFFu + ((v.u >> 16) & 1u)) >> 16);
}

__device__ __forceinline__ void gload_lds16(const void* g, void* l) {
  __builtin_amdgcn_global_load_lds(
      (const __attribute__((address_space(1))) void*)g,
      (__attribute__((address_space(3))) void*)l, 16, 0, 0);
}

// ---------------- small prep kernels ----------------

__global__ void cast_bf16_kernel(const float* __restrict__ in,
                                 unsigned short* __restrict__ out, long n) {
  long i = (long)blockIdx.x * 256 + threadIdx.x;
  if (i < n) out[i] = f2b(in[i]);
}

// T[n][m] = w[n-m] for m<=n else 0;  N=2048, row-major 2048x2048 bf16
__global__ void build_T_kernel(const float* __restrict__ w,
                               unsigned short* __restrict__ T) {
  long i = (long)blockIdx.x * 256 + threadIdx.x;
  int n = (int)(i >> 11);
  int m = (int)(i & 2047);
  float v = (m <= n) ? w[n - m] : 0.0f;
  T[i] = f2b(v);
}

// x (B,2048,1024) f32 -> xT (B,1024,2048) bf16
__global__ void transpose_cast_kernel(const float* __restrict__ x,
                                      unsigned short* __restrict__ xT) {
  __shared__ float tile[32][33];
  int b = blockIdx.z;
  int n0 = blockIdx.y * 32;
  int d0 = blockIdx.x * 32;
  int tx = threadIdx.x;  // 0..31
  int ty = threadIdx.y;  // 0..7
  for (int i = ty; i < 32; i += 8)
    tile[i][tx] = x[((long)b * 2048 + n0 + i) * 1024 + d0 + tx];
  __syncthreads();
  for (int i = ty; i < 32; i += 8)
    xT[((long)b * 1024 + d0 + i) * 2048 + n0 + tx] = f2b(tile[tx][i]);
}

// ---------------- GEMM: C(MxN) = A(MxK) @ B(NxK)^T, bf16 in, f32 acc ----------------
// EPI 1: Cf = resid + scale[row]*acc           (conv epilogue)
// EPI 2: Cb = bf16(gelu(acc + bias[col]))      (MLP up)
// EPI 3: Cf = resid + scalar*(acc + bias[col]) (MLP down)
template <int EPI>
__global__ __launch_bounds__(256, 2) void gemm_bt(
    const unsigned short* __restrict__ A, const unsigned short* __restrict__ B,
    int M, int N, int K, long batchA, long batchB,
    const float* __restrict__ resid, const float* __restrict__ scale,
    const float* __restrict__ bias, const float* __restrict__ scalar_p,
    float* __restrict__ Cf, unsigned short* __restrict__ Cb) {
  __shared__ __align__(16) unsigned short As[128 * 32];
  __shared__ __align__(16) unsigned short Bs[128 * 32];
  const int tid = threadIdx.x;
  const int wid = tid >> 6;
  const int lane = tid & 63;
  const int quad = lane >> 4;
  const int l16 = lane & 15;
  const int wm = (wid >> 1) * 64;
  const int wn = (wid & 1) * 64;
  const long bm = (long)blockIdx.y * 128;
  const long bn = (long)blockIdx.x * 128;
  const int bz = blockIdx.z;
  const unsigned short* Ab = A + batchA * bz;
  const unsigned short* Bb = B + batchB * bz;

  floatx4 acc[4][4];
#pragma unroll
  for (int i = 0; i < 4; ++i)
#pragma unroll
    for (int j = 0; j < 4; ++j)
      acc[i][j] = floatx4{0.0f, 0.0f, 0.0f, 0.0f};

  // staging: 512 chunks of 16B per tile; chunk = pass*256 + tid
  const int c0 = tid, c1 = 256 + tid;
  const int r0 = c0 >> 2, k0c = (c0 & 3) * 8;
  const int r1 = c1 >> 2, k1c = (c1 & 3) * 8;
  unsigned short* lA0 = As + (wid * 64) * 8;         // wave-uniform LDS bases
  unsigned short* lA1 = As + (256 + wid * 64) * 8;
  unsigned short* lB0 = Bs + (wid * 64) * 8;
  unsigned short* lB1 = Bs + (256 + wid * 64) * 8;
  const unsigned short* gA0 = Ab + (bm + r0) * (long)K + k0c;
  const unsigned short* gA1 = Ab + (bm + r1) * (long)K + k1c;
  const unsigned short* gB0 = Bb + (bn + r0) * (long)K + k0c;
  const unsigned short* gB1 = Bb + (bn + r1) * (long)K + k1c;

  for (int kk = 0; kk < K; kk += 32) {
    __syncthreads();
    gload_lds16(gA0 + kk, lA0);
    gload_lds16(gA1 + kk, lA1);
    gload_lds16(gB0 + kk, lB0);
    gload_lds16(gB1 + kk, lB1);
    __syncthreads();
    bf16x8 af[4], bfr[4];
#pragma unroll
    for (int i = 0; i < 4; ++i)
      af[i] = *(const bf16x8*)(As + (wm + i * 16 + l16) * 32 + quad * 8);
#pragma unroll
    for (int j = 0; j < 4; ++j)
      bfr[j] = *(const bf16x8*)(Bs + (wn + j * 16 + l16) * 32 + quad * 8);
#pragma unroll
    for (int i = 0; i < 4; ++i)
#pragma unroll
      for (int j = 0; j < 4; ++j)
        acc[i][j] = __builtin_amdgcn_mfma_f32_16x16x32_bf16(af[i], bfr[j],
                                                            acc[i][j], 0, 0, 0);
  }

  const float scl = (EPI == 3) ? scalar_p[0] : 0.0f;
#pragma unroll
  for (int i = 0; i < 4; ++i) {
#pragma unroll
    for (int j = 0; j < 4; ++j) {
#pragma unroll
      for (int r = 0; r < 4; ++r) {
        long row = bm + wm + i * 16 + quad * 4 + r;
        long col = bn + wn + j * 16 + l16;
        long idx = ((long)bz * M + row) * N + col;
        float v = acc[i][j][r];
        if (EPI == 1) {
          Cf[idx] = resid[idx] + scale[row] * v;
        } else if (EPI == 2) {
          v += bias[col];
          v = 0.5f * v * (1.0f + erff(v * 0.70710678118654752f));
          Cb[idx] = f2b(v);
        } else {
          v += bias[col];
          Cf[idx] = resid[idx] + scl * v;
        }
      }
    }
  }
}

// ---------------- LayerNorm over D=1024, one block per row ----------------
__global__ __launch_bounds__(256) void ln_kernel(
    const float* __restrict__ in, const float* __restrict__ w,
    const float* __restrict__ b, float* __restrict__ outf,
    unsigned short* __restrict__ outb) {
  const long row = blockIdx.x;
  const int tid = threadIdx.x;
  float4 v = ((const float4*)in)[row * 256 + tid];
  float s = v.x + v.y + v.z + v.w;
  float ss = v.x * v.x + v.y * v.y + v.z * v.z + v.w * v.w;
#pragma unroll
  for (int off = 32; off > 0; off >>= 1) {
    s += __shfl_down(s, off);
    ss += __shfl_down(ss, off);
  }
  __shared__ float red[8];
  const int wid = tid >> 6, lane = tid & 63;
  if (lane == 0) { red[wid] = s; red[4 + wid] = ss; }
  __syncthreads();
  s = red[0] + red[1] + red[2] + red[3];
  ss = red[4] + red[5] + red[6] + red[7];
  const float mu = s * (1.0f / 1024.0f);
  const float var = ss * (1.0f / 1024.0f) - mu * mu;
  const float rs = rsqrtf(var + 1e-5f);
  float4 wv = ((const float4*)w)[tid];
  float4 bv = ((const float4*)b)[tid];
  float o0 = (v.x - mu) * rs * wv.x + bv.x;
  float o1 = (v.y - mu) * rs * wv.y + bv.y;
  float o2 = (v.z - mu) * rs * wv.z + bv.z;
  float o3 = (v.w - mu) * rs * wv.w + bv.w;
  if (outf) {
    float4 o{o0, o1, o2, o3};
    ((float4*)outf)[row * 256 + tid] = o;
  }
  if (outb) {
    ushort4 u{f2b(o0), f2b(o1), f2b(o2), f2b(o3)};
    ((ushort4*)outb)[row * 256 + tid] = u;
  }
}

// ---------------- launch ----------------
extern "C" void kernel_launch(void* const* d_in, const int* in_sizes, int n_in,
                              void* d_out, int out_size, void* d_ws, size_t ws_size,
                              hipStream_t stream) {
  const float* x      = (const float*)d_in[0];
  const float* wconv  = (const float*)d_in[1];
  const float* scale  = (const float*)d_in[2];
  const float* ln1w   = (const float*)d_in[3];
  const float* ln1b   = (const float*)d_in[4];
  const float* W1     = (const float*)d_in[5];
  const float* b1     = (const float*)d_in[6];
  const float* W2     = (const float*)d_in[7];
  const float* b2     = (const float*)d_in[8];
  const float* scalar = (const float*)d_in[9];
  const float* ln2w   = (const float*)d_in[10];
  const float* ln2b   = (const float*)d_in[11];
  float* out = (float*)d_out;

  char* ws = (char*)d_ws;
  unsigned short* xT  = (unsigned short*)ws; ws += (size_t)4 * 1024 * 2048 * 2;  // 16 MB
  unsigned short* T   = (unsigned short*)ws; ws += (size_t)2048 * 2048 * 2;      //  8 MB
  unsigned short* W1b = (unsigned short*)ws; ws += (size_t)4096 * 1024 * 2;      //  8 MB
  unsigned short* W2b = (unsigned short*)ws; ws += (size_t)4096 * 1024 * 2;      //  8 MB
  float* y            = (float*)ws;          ws += (size_t)8192 * 1024 * 4;      // 32 MB (conv-out, reused as z)
  float* x1f          = (float*)ws;          ws += (size_t)8192 * 1024 * 4;      // 32 MB
  unsigned short* x1b = (unsigned short*)ws; ws += (size_t)8192 * 1024 * 2;      // 16 MB
  unsigned short* h   = (unsigned short*)ws; ws += (size_t)8192 * 4096 * 2;      // 64 MB

  // prep: weight casts, Toeplitz build, x transpose+cast
  cast_bf16_kernel<<<16384, 256, 0, stream>>>(W1, W1b, (long)4096 * 1024);
  cast_bf16_kernel<<<16384, 256, 0, stream>>>(W2, W2b, (long)4096 * 1024);
  build_T_kernel<<<16384, 256, 0, stream>>>(wconv, T);
  transpose_cast_kernel<<<dim3(32, 64, 4), dim3(32, 8), 0, stream>>>(x, xT);

  // GEMM1: per batch, conv = T(2048x2048) @ xT_b(1024x2048)^T ; y = x + scale*conv
  gemm_bt<1><<<dim3(8, 16, 4), 256, 0, stream>>>(
      T, xT, 2048, 1024, 2048, 0L, (long)1024 * 2048,
      x, scale, nullptr, nullptr, y, nullptr);
  // LN1 -> x1 (f32 + bf16)
  ln_kernel<<<8192, 256, 0, stream>>>(y, ln1w, ln1b, x1f, x1b);
  // GEMM2: h = gelu(x1(8192x1024) @ W1(4096x1024)^T + b1) -> bf16
  gemm_bt<2><<<dim3(32, 64, 1), 256, 0, stream>>>(
      x1b, W1b, 8192, 4096, 1024, 0L, 0L,
      nullptr, nullptr, b1, nullptr, nullptr, h);
  // GEMM3: z = x1 + scalar*(h(8192x4096) @ W2(1024x4096)^T + b2)
  gemm_bt<3><<<dim3(8, 64, 1), 256, 0, stream>>>(
      h, W2b, 8192, 1024, 4096, 0L, 0L,
      x1f, nullptr, b2, scalar, y, nullptr);
  // LN2 -> out
  ln_kernel<<<8192, 256, 0, stream>>>(y, ln2w, ln2b, out, nullptr);
}